// Round 25
// baseline (122.392 us; speedup 1.0000x reference)
//
#include <hip/hip_runtime.h>
#include <hip/hip_bf16.h>
#include <math.h>

#define TWO_PI 6.28318530717958647692f
#define PI_F   3.14159265358979323846f
#define NORM   0.0078125f  /* 1/sqrt(128*128) */

typedef float v2f  __attribute__((ext_vector_type(2)));
typedef short sh8  __attribute__((ext_vector_type(8)));
typedef float f32x4 __attribute__((ext_vector_type(4)));

__device__ __forceinline__ unsigned short f2bf(float f) {
    unsigned int u = __float_as_uint(f);
    unsigned int r = (u + 0x7FFFu + ((u >> 16) & 1u)) >> 16;   // RNE
    return (unsigned short)r;
}

__device__ __forceinline__ sh8 pack8(float4 a, float4 b) {
    __hip_bfloat162 p0 = __float22bfloat162_rn(make_float2(a.x, a.y));
    __hip_bfloat162 p1 = __float22bfloat162_rn(make_float2(a.z, a.w));
    __hip_bfloat162 p2 = __float22bfloat162_rn(make_float2(b.x, b.y));
    __hip_bfloat162 p3 = __float22bfloat162_rn(make_float2(b.z, b.w));
    uint4 u = make_uint4(*reinterpret_cast<unsigned int*>(&p0),
                         *reinterpret_cast<unsigned int*>(&p1),
                         *reinterpret_cast<unsigned int*>(&p2),
                         *reinterpret_cast<unsigned int*>(&p3));
    return *reinterpret_cast<sh8*>(&u);
}

// ---------------------------------------------------------------- tables
// wb[j<16][k<128] bf16 (fwd p1, j>=11 zero); pb = 3 tables [i32][n128] bf16 {Pr,Pi,-Pi} (fwd p2);
// qxb = 3 tables [n][i32] bf16 {re,im,-im} (inv A); qtb = 2 tables [m][k32] bf16 (inv B)
__device__ __forceinline__ float kfreq(int i) { return (i <= 10) ? (float)i : (float)(i - 21); }

__global__ void k_tables(const float* __restrict__ thrx, const float* __restrict__ thrt,
                         unsigned short* __restrict__ wb, unsigned short* __restrict__ pb,
                         unsigned short* __restrict__ qxb, unsigned short* __restrict__ qtb) {
    int t = threadIdx.x;
    for (int z = t; z < 2048; z += 256) {
        int j = z >> 7, k = z & 127;
        float ang = -TWO_PI * (float)((j * k) & 127) * (1.0f / 128.0f);
        float s, c; sincosf(ang, &s, &c);
        bool valid = (j < 11);
        wb[z]        = valid ? f2bf(c) : (unsigned short)0;
        wb[z + 2048] = valid ? f2bf(s) : (unsigned short)0;
    }
    for (int z = t; z < 3 * 4096; z += 256) {        // pb: Pr, Pi, -Pi [i32][n128]
        int tbl = z >> 12, rem = z & 4095;
        int i = rem >> 7, n = rem & 127;
        bool valid = (i < 21);
        int kk = (i <= 10) ? i : i + 107;
        float ang = -TWO_PI * (float)((kk * n) & 127) * (1.0f / 128.0f);
        float s, c; sincosf(ang, &s, &c);
        float v = (tbl == 0) ? c : ((tbl == 1) ? s : -s);
        pb[z] = valid ? f2bf(v) : (unsigned short)0;
    }
    for (int idx = t; idx < 21 * 128; idx += 256) {
        int i = idx >> 7, n = idx & 127;
        float k = kfreq(i), fn = (float)n;
        float s, c;
        {
            float raw = thrx[i];
            float sig = 1.0f / (1.0f + expf(-raw));
            float th = (k < 0.0f) ? (0.5f * PI_F) * (1.0f + sig) : PI_F * sig;
            float ka = fabsf(k);
            float amp = expf(-TWO_PI * ka * sinf(th) * fn * (1.0f / 128.0f));
            float a2 = TWO_PI * ka * cosf(th) * fn * (1.0f / 128.0f);
            sincosf(a2, &s, &c);
            qxb[n * 32 + i]        = f2bf(amp * c);
            qxb[4096 + n * 32 + i] = f2bf(amp * s);
            qxb[8192 + n * 32 + i] = f2bf(-amp * s);
        }
        {
            float raw = thrt[i];
            float sig = 1.0f / (1.0f + expf(-raw));
            float th = (k < 0.0f) ? (0.5f * PI_F) * (1.0f + sig) : PI_F * sig;
            float ka = fabsf(k);
            float amp = expf(-TWO_PI * ka * sinf(th) * fn * (1.0f / 128.0f));
            float a2 = TWO_PI * ka * cosf(th) * fn * (1.0f / 128.0f);
            sincosf(a2, &s, &c);
            qtb[n * 32 + i]        = f2bf(amp * c);
            qtb[4096 + n * 32 + i] = f2bf(amp * s);
        }
    }
    for (int z = t; z < 128 * 11; z += 256) {
        int n = z / 11, kz = 21 + z % 11;
        qxb[n * 32 + kz] = 0;
        qxb[4096 + n * 32 + kz] = 0;
        qxb[8192 + n * 32 + kz] = 0;
        qtb[n * 32 + kz] = 0;
        qtb[4096 + n * 32 + kz] = 0;
    }
}

// ---------------------------------------------------------------- weight transpose [co][ij] -> [ij][co]  [frozen]
__global__ void k_wt(const float* __restrict__ wr, const float* __restrict__ wi,
                     float2* __restrict__ Rt) {
    __shared__ float2 tile[64][65];
    const int tx = threadIdx.x & 63;
    const int ty = threadIdx.x >> 6;
    const int ij0 = blockIdx.x * 64;
    const int co0 = blockIdx.y * 64;
    #pragma unroll
    for (int r = 0; r < 16; ++r) {
        int row = ty + r * 4;
        int col = ij0 + tx;
        if (col < 441) {
            size_t g = (size_t)(co0 + row) * 441 + col;
            tile[row][tx] = make_float2(wr[g], wi[g]);
        }
    }
    __syncthreads();
    #pragma unroll
    for (int r = 0; r < 16; ++r) {
        int row = ty + r * 4;
        int ij = ij0 + row;
        if (ij < 441)
            Rt[(size_t)ij * 4096 + co0 + tx] = tile[tx][row];
    }
}

// ---------------------------------------------------------------- forward DFT (per b,c)
// phase 1: A from global x (pk-convert in regs), B = wb LDS tables -> T1 bf16 [j][136] LDS.
// phase 2: MFMA, A = P tables DIRECT FROM GLOBAL, B = T1 LDS. Conj-fill epilogue.
__launch_bounds__(256, 4)
__global__ void k_fwd(const float* __restrict__ x, const unsigned short* __restrict__ wbg,
                      const unsigned short* __restrict__ pbg, float2* __restrict__ Xt) {
    __shared__ __align__(16) unsigned short t1br[16 * 136];    // 4352 B
    __shared__ __align__(16) unsigned short t1bi[16 * 136];    // 4352 B
    __shared__ __align__(16) unsigned short wbs[2][16 * 136];  // 8704 B
    __shared__ float xrf[512];                                 // [i32][j16]
    __shared__ float xif[512];
    const int t = threadIdx.x;
    const int bid = blockIdx.x;
    const int bc = (bid & 7) * 256 + (bid >> 3);               // XCD swizzle
    const int lane = t & 63;
    const int w = t >> 6;
    const int c16 = lane & 15, q = lane >> 4;

    const float* xg = x + (size_t)bc * 16384;
    for (int k = t; k < 512; k += 256) {                       // stage wb tables, padded rows
        int tbl = k >> 8, c = k & 255;
        int row = c >> 4, ch = c & 15;
        *reinterpret_cast<uint4*>(&wbs[tbl][row * 136 + ch * 8]) =
            *reinterpret_cast<const uint4*>(wbg + tbl * 2048 + row * 128 + ch * 8);
    }
    __syncthreads();
    // phase 1: wave w owns rows 32w..32w+31; A direct from global
    f32x4 aR0 = (f32x4)(0.f), aI0 = (f32x4)(0.f), aR1 = (f32x4)(0.f), aI1 = (f32x4)(0.f);
    {
        const float* arow0 = xg + (32 * w + c16) * 128 + 8 * q;
        const float* arow1 = arow0 + 16 * 128;
        const unsigned short* brow = &wbs[0][c16 * 136 + 8 * q];
        const unsigned short* irow = &wbs[1][c16 * 136 + 8 * q];
#define P1(ks) { \
        float4 va0 = *reinterpret_cast<const float4*>(arow0 + ks * 32); \
        float4 vb0 = *reinterpret_cast<const float4*>(arow0 + ks * 32 + 4); \
        float4 va1 = *reinterpret_cast<const float4*>(arow1 + ks * 32); \
        float4 vb1 = *reinterpret_cast<const float4*>(arow1 + ks * 32 + 4); \
        sh8 a0 = pack8(va0, vb0); \
        sh8 a1 = pack8(va1, vb1); \
        sh8 br = *reinterpret_cast<const sh8*>(brow + ks * 32); \
        sh8 bi = *reinterpret_cast<const sh8*>(irow + ks * 32); \
        aR0 = __builtin_amdgcn_mfma_f32_16x16x32_bf16(a0, br, aR0, 0, 0, 0); \
        aI0 = __builtin_amdgcn_mfma_f32_16x16x32_bf16(a0, bi, aI0, 0, 0, 0); \
        aR1 = __builtin_amdgcn_mfma_f32_16x16x32_bf16(a1, br, aR1, 0, 0, 0); \
        aI1 = __builtin_amdgcn_mfma_f32_16x16x32_bf16(a1, bi, aI1, 0, 0, 0); }
        P1(0) P1(1) P1(2) P1(3)
#undef P1
    }
    // write T1 as bf16 [j][136] tables (j = c16)
    #pragma unroll
    for (int reg = 0; reg < 4; ++reg) {
        int n0 = 32 * w + 4 * q + reg, n1 = n0 + 16;
        t1br[c16 * 136 + n0] = f2bf(aR0[reg]);
        t1bi[c16 * 136 + n0] = f2bf(aI0[reg]);
        t1br[c16 * 136 + n1] = f2bf(aR1[reg]);
        t1bi[c16 * 136 + n1] = f2bf(aI1[reg]);
    }
    __syncthreads();
    // phase 2: MFMA, A-frags direct from global pb tables. wave w: i-tile = w&1, part = w>>1.
    {
        const unsigned short* Pr  = pbg;
        const unsigned short* Pi_ = pbg + 4096;
        const unsigned short* Pn  = pbg + 8192;
        const int it1 = w & 1, part = w >> 1;
        const unsigned short* aF = Pr + (16 * it1 + c16) * 128 + 8 * q;
        const unsigned short* aS = (part ? Pi_ : Pn) + (16 * it1 + c16) * 128 + 8 * q;
        const unsigned short* bF = (part ? t1bi : t1br) + c16 * 136 + 8 * q;
        const unsigned short* bS = (part ? t1br : t1bi) + c16 * 136 + 8 * q;
        f32x4 acc = (f32x4)(0.f);
        #pragma unroll
        for (int ks = 0; ks < 4; ++ks) {
            sh8 a1 = *reinterpret_cast<const sh8*>(aF + ks * 32);
            sh8 b1 = *reinterpret_cast<const sh8*>(bF + ks * 32);
            sh8 a2 = *reinterpret_cast<const sh8*>(aS + ks * 32);
            sh8 b2 = *reinterpret_cast<const sh8*>(bS + ks * 32);
            acc = __builtin_amdgcn_mfma_f32_16x16x32_bf16(a1, b1, acc, 0, 0, 0);
            acc = __builtin_amdgcn_mfma_f32_16x16x32_bf16(a2, b2, acc, 0, 0, 0);
        }
        float* dst = part ? xif : xrf;
        #pragma unroll
        for (int reg = 0; reg < 4; ++reg)
            dst[(16 * it1 + 4 * q + reg) * 16 + c16] = acc[reg];
    }
    __syncthreads();
    for (int p = t; p < 441; p += 256) {
        int i = p / 21, j = p % 21;
        float re, im;
        if (j < 11) { re = xrf[i * 16 + j]; im = xif[i * 16 + j]; }
        else {
            int i2 = (21 - i) % 21, j2 = 21 - j;
            re = xrf[i2 * 16 + j2]; im = -xif[i2 * 16 + j2];
        }
        Xt[(size_t)p * 2048 + bc] = make_float2(re * NORM, im * NORM);
    }
}

// ---------------------------------------------------------------- channel mix (per mode)  [frozen, round-22]
__launch_bounds__(256, 4)
__global__ void k_mix(const float2* __restrict__ Xt, const float2* __restrict__ Rt,
                      float2* __restrict__ OK) {
    __shared__ __align__(16) unsigned short xbr[32 * 72];
    __shared__ __align__(16) unsigned short xbi[32 * 72];
    __shared__ __align__(16) unsigned short rsr[64 * 72];
    __shared__ __align__(16) unsigned short rsi[64 * 72];
    __shared__ __align__(16) unsigned short rsn[64 * 72];
    const int t = threadIdx.x;
    const int ij = blockIdx.x;
    for (int k = t; k < 2048; k += 256) {
        float2 v = Xt[(size_t)ij * 2048 + k];
        int b = k >> 6, c = k & 63;
        xbr[b * 72 + c] = f2bf(v.x);
        xbi[b * 72 + c] = f2bf(v.y);
    }
    for (int k = t; k < 4096; k += 256) {
        float2 v = Rt[(size_t)ij * 4096 + k];
        int c = k >> 6, o = k & 63;
        rsr[o * 72 + c] = f2bf(v.x);
        rsi[o * 72 + c] = f2bf(v.y);
        rsn[o * 72 + c] = f2bf(-v.y);
    }
    __syncthreads();
    const int lane = t & 63, w = t >> 6;
    const int c16 = lane & 15, q = lane >> 4;
    f32x4 aR0 = (f32x4)(0.f), aI0 = (f32x4)(0.f), aR1 = (f32x4)(0.f), aI1 = (f32x4)(0.f);
    #pragma unroll
    for (int ks = 0; ks < 2; ++ks) {
        const int off = ks * 32 + 8 * q;
        sh8 xr0 = *reinterpret_cast<const sh8*>(&xbr[c16 * 72 + off]);
        sh8 xr1 = *reinterpret_cast<const sh8*>(&xbr[(16 + c16) * 72 + off]);
        sh8 xi0 = *reinterpret_cast<const sh8*>(&xbi[c16 * 72 + off]);
        sh8 xi1 = *reinterpret_cast<const sh8*>(&xbi[(16 + c16) * 72 + off]);
        sh8 br = *reinterpret_cast<const sh8*>(&rsr[(16 * w + c16) * 72 + off]);
        sh8 bi = *reinterpret_cast<const sh8*>(&rsi[(16 * w + c16) * 72 + off]);
        sh8 bn = *reinterpret_cast<const sh8*>(&rsn[(16 * w + c16) * 72 + off]);
        aR0 = __builtin_amdgcn_mfma_f32_16x16x32_bf16(xr0, br, aR0, 0, 0, 0);
        aR0 = __builtin_amdgcn_mfma_f32_16x16x32_bf16(xi0, bn, aR0, 0, 0, 0);
        aI0 = __builtin_amdgcn_mfma_f32_16x16x32_bf16(xr0, bi, aI0, 0, 0, 0);
        aI0 = __builtin_amdgcn_mfma_f32_16x16x32_bf16(xi0, br, aI0, 0, 0, 0);
        aR1 = __builtin_amdgcn_mfma_f32_16x16x32_bf16(xr1, br, aR1, 0, 0, 0);
        aR1 = __builtin_amdgcn_mfma_f32_16x16x32_bf16(xi1, bn, aR1, 0, 0, 0);
        aI1 = __builtin_amdgcn_mfma_f32_16x16x32_bf16(xr1, bi, aI1, 0, 0, 0);
        aI1 = __builtin_amdgcn_mfma_f32_16x16x32_bf16(xi1, br, aI1, 0, 0, 0);
    }
    float2* okrow = OK + (size_t)ij * 2048;
    #pragma unroll
    for (int reg = 0; reg < 4; ++reg) {
        okrow[(4 * q + reg) * 64 + 16 * w + c16]        = make_float2(aR0[reg], aI0[reg]);
        okrow[(16 + 4 * q + reg) * 64 + 16 * w + c16]   = make_float2(aR1[reg], aI1[reg]);
    }
}

// ---------------------------------------------------------------- inverse DFT (per b,o)  [frozen, round-24]
__launch_bounds__(256, 5)
__global__ void k_inv(const float2* __restrict__ OKg, const unsigned short* __restrict__ qxbg,
                      const unsigned short* __restrict__ qtbg, float* __restrict__ out) {
    __shared__ __align__(16) unsigned short t2br[4096];
    __shared__ __align__(16) unsigned short t2bi[4096];
    __shared__ __align__(16) unsigned short okr_t[1024];
    __shared__ __align__(16) unsigned short oki_t[1024];
    __shared__ float2 oks[441];
    const int t = threadIdx.x;
    const int bo = blockIdx.x;

    for (int k = t; k < 441; k += 256) oks[k] = OKg[(size_t)k * 2048 + bo];
    __syncthreads();
    for (int k = t; k < 1024; k += 256) {
        int j = k >> 5, i = k & 31;
        bool v = (j < 21) && (i < 21);
        float2 o = v ? oks[i * 21 + j] : make_float2(0.f, 0.f);
        okr_t[k] = v ? f2bf(o.x) : (unsigned short)0;
        oki_t[k] = v ? f2bf(o.y) : (unsigned short)0;
    }
    __syncthreads();
    const int lane = t & 63, w = t >> 6;
    const int c16 = lane & 15, q = lane >> 4;
    {
        const unsigned short* qxr = qxbg;
        const unsigned short* qxi = qxbg + 4096;
        const unsigned short* qxn = qxbg + 8192;
        sh8 ar0 = *reinterpret_cast<const sh8*>(okr_t + c16 * 32 + 8 * q);
        sh8 ar1 = *reinterpret_cast<const sh8*>(okr_t + (16 + c16) * 32 + 8 * q);
        sh8 ai0 = *reinterpret_cast<const sh8*>(oki_t + c16 * 32 + 8 * q);
        sh8 ai1 = *reinterpret_cast<const sh8*>(oki_t + (16 + c16) * 32 + 8 * q);
        #pragma unroll
        for (int nn = 0; nn < 2; ++nn) {
            int nt = 2 * w + nn;
            int nb = (16 * nt + c16) * 32 + 8 * q;
            sh8 br = *reinterpret_cast<const sh8*>(qxr + nb);
            sh8 bi = *reinterpret_cast<const sh8*>(qxi + nb);
            sh8 bn = *reinterpret_cast<const sh8*>(qxn + nb);
            f32x4 aR0 = (f32x4)(0.f), aI0 = (f32x4)(0.f);
            f32x4 aR1 = (f32x4)(0.f), aI1 = (f32x4)(0.f);
            aR0 = __builtin_amdgcn_mfma_f32_16x16x32_bf16(ar0, br, aR0, 0, 0, 0);
            aR0 = __builtin_amdgcn_mfma_f32_16x16x32_bf16(ai0, bn, aR0, 0, 0, 0);
            aI0 = __builtin_amdgcn_mfma_f32_16x16x32_bf16(ar0, bi, aI0, 0, 0, 0);
            aI0 = __builtin_amdgcn_mfma_f32_16x16x32_bf16(ai0, br, aI0, 0, 0, 0);
            aR1 = __builtin_amdgcn_mfma_f32_16x16x32_bf16(ar1, br, aR1, 0, 0, 0);
            aR1 = __builtin_amdgcn_mfma_f32_16x16x32_bf16(ai1, bn, aR1, 0, 0, 0);
            aI1 = __builtin_amdgcn_mfma_f32_16x16x32_bf16(ar1, bi, aI1, 0, 0, 0);
            aI1 = __builtin_amdgcn_mfma_f32_16x16x32_bf16(ai1, br, aI1, 0, 0, 0);
            int nrow = (16 * nt + c16) * 32;
            #pragma unroll
            for (int reg = 0; reg < 4; ++reg) {
                t2br[nrow + 4 * q + reg]      = f2bf(aR0[reg]);
                t2bi[nrow + 4 * q + reg]      = f2bf(-aI0[reg]);
                t2br[nrow + 16 + 4 * q + reg] = f2bf(aR1[reg]);
                t2bi[nrow + 16 + 4 * q + reg] = f2bf(-aI1[reg]);
            }
        }
    }
    __syncthreads();
    {
        const unsigned short* qtbr_l = qtbg;
        const unsigned short* qtbi_l = qtbg + 4096;
        sh8 ar0 = *reinterpret_cast<const sh8*>(t2br + (32 * w + c16) * 32 + 8 * q);
        sh8 ai0 = *reinterpret_cast<const sh8*>(t2bi + (32 * w + c16) * 32 + 8 * q);
        sh8 ar1 = *reinterpret_cast<const sh8*>(t2br + (32 * w + 16 + c16) * 32 + 8 * q);
        sh8 ai1 = *reinterpret_cast<const sh8*>(t2bi + (32 * w + 16 + c16) * 32 + 8 * q);
        float* og = out + (size_t)bo * 16384;
        #pragma unroll
        for (int mc = 0; mc < 8; ++mc) {
            sh8 br = *reinterpret_cast<const sh8*>(qtbr_l + (16 * mc + c16) * 32 + 8 * q);
            sh8 bi = *reinterpret_cast<const sh8*>(qtbi_l + (16 * mc + c16) * 32 + 8 * q);
            f32x4 acc0 = (f32x4)(0.f);
            acc0 = __builtin_amdgcn_mfma_f32_16x16x32_bf16(ar0, br, acc0, 0, 0, 0);
            acc0 = __builtin_amdgcn_mfma_f32_16x16x32_bf16(ai0, bi, acc0, 0, 0, 0);
            f32x4 acc1 = (f32x4)(0.f);
            acc1 = __builtin_amdgcn_mfma_f32_16x16x32_bf16(ar1, br, acc1, 0, 0, 0);
            acc1 = __builtin_amdgcn_mfma_f32_16x16x32_bf16(ai1, bi, acc1, 0, 0, 0);
            #pragma unroll
            for (int reg = 0; reg < 4; ++reg) {
                og[(32 * w + 4 * q + reg) * 128 + 16 * mc + c16]      = acc0[reg] * NORM;
                og[(32 * w + 16 + 4 * q + reg) * 128 + 16 * mc + c16] = acc1[reg] * NORM;
            }
        }
    }
}

// ---------------------------------------------------------------- launch
extern "C" void kernel_launch(void* const* d_in, const int* in_sizes, int n_in,
                              void* d_out, int out_size, void* d_ws, size_t ws_size,
                              hipStream_t stream) {
    const float* x   = (const float*)d_in[0];
    const float* wr  = (const float*)d_in[1];
    const float* wi  = (const float*)d_in[2];
    const float* thx = (const float*)d_in[3];
    const float* tht = (const float*)d_in[4];
    float* out = (float*)d_out;

    char* ws = (char*)d_ws;
    unsigned short* wb  = (unsigned short*)(ws + 1024);           // 8192 B
    unsigned short* qxb = (unsigned short*)(ws + 9216);           // 24576 B
    unsigned short* qtb = (unsigned short*)(ws + 33792);          // 16384 B (ends 50176 < 64512)
    float2* Rt = (float2*)(ws + 64512);                           // 14450688 B
    float2* Xt = (float2*)(ws + 64512 + 14450688);                // 7340032 B
    float2* OK = (float2*)(ws + 64512 + 14450688 + 7340032);      // 7225344 B
    unsigned short* pb = (unsigned short*)(ws + 64512 + 14450688 + 7340032 + 7225344);  // 24576 B

    k_tables<<<1, 256, 0, stream>>>(thx, tht, wb, pb, qxb, qtb);
    k_wt<<<dim3(7, 64), 256, 0, stream>>>(wr, wi, Rt);
    k_fwd<<<2048, 256, 0, stream>>>(x, wb, pb, Xt);
    k_mix<<<441, 256, 0, stream>>>(Xt, Rt, OK);
    k_inv<<<2048, 256, 0, stream>>>(OK, qxb, qtb, out);
}

// Round 26
// 101.510 us; speedup vs baseline: 1.2057x; 1.2057x over previous
//
#include <hip/hip_runtime.h>
#include <hip/hip_bf16.h>
#include <math.h>

#define TWO_PI 6.28318530717958647692f
#define PI_F   3.14159265358979323846f
#define NORM   0.0078125f  /* 1/sqrt(128*128) */

typedef float v2f  __attribute__((ext_vector_type(2)));
typedef short sh8  __attribute__((ext_vector_type(8)));
typedef float f32x4 __attribute__((ext_vector_type(4)));

__device__ __forceinline__ unsigned short f2bf(float f) {
    unsigned int u = __float_as_uint(f);
    unsigned int r = (u + 0x7FFFu + ((u >> 16) & 1u)) >> 16;   // RNE
    return (unsigned short)r;
}

__device__ __forceinline__ sh8 pack8(float4 a, float4 b) {
    __hip_bfloat162 p0 = __float22bfloat162_rn(make_float2(a.x, a.y));
    __hip_bfloat162 p1 = __float22bfloat162_rn(make_float2(a.z, a.w));
    __hip_bfloat162 p2 = __float22bfloat162_rn(make_float2(b.x, b.y));
    __hip_bfloat162 p3 = __float22bfloat162_rn(make_float2(b.z, b.w));
    uint4 u = make_uint4(*reinterpret_cast<unsigned int*>(&p0),
                         *reinterpret_cast<unsigned int*>(&p1),
                         *reinterpret_cast<unsigned int*>(&p2),
                         *reinterpret_cast<unsigned int*>(&p3));
    return *reinterpret_cast<sh8*>(&u);
}

// ---------------------------------------------------------------- prep: tables (block 0) + weight transpose (blocks 1..448)
__device__ __forceinline__ float kfreq(int i) { return (i <= 10) ? (float)i : (float)(i - 21); }

__global__ void k_prep(const float* __restrict__ thrx, const float* __restrict__ thrt,
                       const float* __restrict__ wr, const float* __restrict__ wi,
                       float2* __restrict__ W1, unsigned short* __restrict__ wb,
                       unsigned short* __restrict__ qxb, unsigned short* __restrict__ qtb,
                       float2* __restrict__ Rt) {
    __shared__ float2 tile[64][65];
    const int t = threadIdx.x;
    if (blockIdx.x == 0) {
        if (t < 128) {
            float s, c;
            float ang = -TWO_PI * (float)t * (1.0f / 128.0f);
            sincosf(ang, &s, &c);
            W1[t] = make_float2(c, s);
        }
        for (int z = t; z < 2048; z += 256) {
            int j = z >> 7, k = z & 127;
            float ang = -TWO_PI * (float)((j * k) & 127) * (1.0f / 128.0f);
            float s, c; sincosf(ang, &s, &c);
            bool valid = (j < 11);
            wb[z]        = valid ? f2bf(c) : (unsigned short)0;
            wb[z + 2048] = valid ? f2bf(s) : (unsigned short)0;
        }
        for (int idx = t; idx < 21 * 128; idx += 256) {
            int i = idx >> 7, n = idx & 127;
            float k = kfreq(i), fn = (float)n;
            float s, c;
            {
                float raw = thrx[i];
                float sig = 1.0f / (1.0f + expf(-raw));
                float th = (k < 0.0f) ? (0.5f * PI_F) * (1.0f + sig) : PI_F * sig;
                float ka = fabsf(k);
                float amp = expf(-TWO_PI * ka * sinf(th) * fn * (1.0f / 128.0f));
                float a2 = TWO_PI * ka * cosf(th) * fn * (1.0f / 128.0f);
                sincosf(a2, &s, &c);
                qxb[n * 32 + i]        = f2bf(amp * c);
                qxb[4096 + n * 32 + i] = f2bf(amp * s);
                qxb[8192 + n * 32 + i] = f2bf(-amp * s);
            }
            {
                float raw = thrt[i];
                float sig = 1.0f / (1.0f + expf(-raw));
                float th = (k < 0.0f) ? (0.5f * PI_F) * (1.0f + sig) : PI_F * sig;
                float ka = fabsf(k);
                float amp = expf(-TWO_PI * ka * sinf(th) * fn * (1.0f / 128.0f));
                float a2 = TWO_PI * ka * cosf(th) * fn * (1.0f / 128.0f);
                sincosf(a2, &s, &c);
                qtb[n * 32 + i]        = f2bf(amp * c);
                qtb[4096 + n * 32 + i] = f2bf(amp * s);
            }
        }
        for (int z = t; z < 128 * 11; z += 256) {
            int n = z / 11, kz = 21 + z % 11;
            qxb[n * 32 + kz] = 0;
            qxb[4096 + n * 32 + kz] = 0;
            qxb[8192 + n * 32 + kz] = 0;
            qtb[n * 32 + kz] = 0;
            qtb[4096 + n * 32 + kz] = 0;
        }
    } else {
        const int b = blockIdx.x - 1;
        const int tx = t & 63;
        const int ty = t >> 6;
        const int ij0 = (b % 7) * 64;
        const int co0 = (b / 7) * 64;
        #pragma unroll
        for (int r = 0; r < 16; ++r) {
            int row = ty + r * 4;
            int col = ij0 + tx;
            if (col < 441) {
                size_t g = (size_t)(co0 + row) * 441 + col;
                tile[row][tx] = make_float2(wr[g], wi[g]);
            }
        }
        __syncthreads();
        #pragma unroll
        for (int r = 0; r < 16; ++r) {
            int row = ty + r * 4;
            int ij = ij0 + row;
            if (ij < 441)
                Rt[(size_t)ij * 4096 + co0 + tx] = tile[tx][row];
        }
    }
}

// ---------------------------------------------------------------- forward DFT (per b,c)  [frozen, round-23/24]
__launch_bounds__(256, 4)
__global__ void k_fwd(const float* __restrict__ x, const float2* __restrict__ W1,
                      const unsigned short* __restrict__ wbg, float2* __restrict__ Xt) {
    __shared__ __align__(16) float2 t1s[128 * 16];
    __shared__ __align__(16) unsigned short wbs[2][16 * 136];
    __shared__ __align__(16) float2 W1s[512];
    __shared__ float2 xout[231];
    const int t = threadIdx.x;
    const int bid = blockIdx.x;
    const int bc = (bid & 7) * 256 + (bid >> 3);
    const int lane = t & 63;
    const int w = t >> 6;
    const int c16 = lane & 15, q = lane >> 4;

    const float* xg = x + (size_t)bc * 16384;
    for (int k = t; k < 512; k += 256) {
        int tbl = k >> 8, c = k & 255;
        int row = c >> 4, ch = c & 15;
        *reinterpret_cast<uint4*>(&wbs[tbl][row * 136 + ch * 8]) =
            *reinterpret_cast<const uint4*>(wbg + tbl * 2048 + row * 128 + ch * 8);
    }
    {
        float4 v = reinterpret_cast<const float4*>(W1)[t & 63];
        reinterpret_cast<float4*>(W1s)[t] = v;
    }
    __syncthreads();
    f32x4 aR0 = (f32x4)(0.f), aI0 = (f32x4)(0.f), aR1 = (f32x4)(0.f), aI1 = (f32x4)(0.f);
    {
        const float* arow0 = xg + (32 * w + c16) * 128 + 8 * q;
        const float* arow1 = arow0 + 16 * 128;
        const unsigned short* brow = &wbs[0][c16 * 136 + 8 * q];
        const unsigned short* irow = &wbs[1][c16 * 136 + 8 * q];
#define P1(ks) { \
        float4 va0 = *reinterpret_cast<const float4*>(arow0 + ks * 32); \
        float4 vb0 = *reinterpret_cast<const float4*>(arow0 + ks * 32 + 4); \
        float4 va1 = *reinterpret_cast<const float4*>(arow1 + ks * 32); \
        float4 vb1 = *reinterpret_cast<const float4*>(arow1 + ks * 32 + 4); \
        sh8 a0 = pack8(va0, vb0); \
        sh8 a1 = pack8(va1, vb1); \
        sh8 br = *reinterpret_cast<const sh8*>(brow + ks * 32); \
        sh8 bi = *reinterpret_cast<const sh8*>(irow + ks * 32); \
        aR0 = __builtin_amdgcn_mfma_f32_16x16x32_bf16(a0, br, aR0, 0, 0, 0); \
        aI0 = __builtin_amdgcn_mfma_f32_16x16x32_bf16(a0, bi, aI0, 0, 0, 0); \
        aR1 = __builtin_amdgcn_mfma_f32_16x16x32_bf16(a1, br, aR1, 0, 0, 0); \
        aI1 = __builtin_amdgcn_mfma_f32_16x16x32_bf16(a1, bi, aI1, 0, 0, 0); }
        P1(0) P1(1) P1(2) P1(3)
#undef P1
    }
    #pragma unroll
    for (int reg = 0; reg < 4; ++reg) {
        t1s[(32 * w + 4 * q + reg) * 16 + c16]      = make_float2(aR0[reg], aI0[reg]);
        t1s[(32 * w + 16 + 4 * q + reg) * 16 + c16] = make_float2(aR1[reg], aI1[reg]);
    }
    __syncthreads();
    const char* W1b = reinterpret_cast<const char*>(W1s);
    if (t < 231) {
        int i = t / 11, j = t % 11;
        int kk = (i <= 10) ? i : i + 107;
        int ib = 0;
        v2f acc = (v2f)(0.f);
        #pragma unroll 4
        for (int nn = 0; nn < 128; ++nn) {
            float2 pv = *reinterpret_cast<const float2*>(W1b + ib);
            float2 tv = t1s[nn * 16 + j];
            v2f tp; tp.x = tv.x; tp.y = tv.y;
            v2f tn; tn.x = -tv.y; tn.y = tv.x;
            acc += tp * pv.x;
            acc += tn * pv.y;
            ib = (ib + kk * 8) & 1023;
        }
        xout[i * 11 + j] = make_float2(acc.x * NORM, acc.y * NORM);
    }
    __syncthreads();
    for (int p = t; p < 441; p += 256) {
        int i = p / 21, j = p % 21;
        float2 v;
        if (j < 11) v = xout[i * 11 + j];
        else {
            float2 u = xout[((21 - i) % 21) * 11 + (21 - j)];
            v = make_float2(u.x, -u.y);
        }
        Xt[(size_t)p * 2048 + bc] = v;
    }
}

// ---------------------------------------------------------------- channel mix (per mode)  [frozen, round-22]
__launch_bounds__(256, 4)
__global__ void k_mix(const float2* __restrict__ Xt, const float2* __restrict__ Rt,
                      float2* __restrict__ OK) {
    __shared__ __align__(16) unsigned short xbr[32 * 72];
    __shared__ __align__(16) unsigned short xbi[32 * 72];
    __shared__ __align__(16) unsigned short rsr[64 * 72];
    __shared__ __align__(16) unsigned short rsi[64 * 72];
    __shared__ __align__(16) unsigned short rsn[64 * 72];
    const int t = threadIdx.x;
    const int ij = blockIdx.x;
    for (int k = t; k < 2048; k += 256) {
        float2 v = Xt[(size_t)ij * 2048 + k];
        int b = k >> 6, c = k & 63;
        xbr[b * 72 + c] = f2bf(v.x);
        xbi[b * 72 + c] = f2bf(v.y);
    }
    for (int k = t; k < 4096; k += 256) {
        float2 v = Rt[(size_t)ij * 4096 + k];
        int c = k >> 6, o = k & 63;
        rsr[o * 72 + c] = f2bf(v.x);
        rsi[o * 72 + c] = f2bf(v.y);
        rsn[o * 72 + c] = f2bf(-v.y);
    }
    __syncthreads();
    const int lane = t & 63, w = t >> 6;
    const int c16 = lane & 15, q = lane >> 4;
    f32x4 aR0 = (f32x4)(0.f), aI0 = (f32x4)(0.f), aR1 = (f32x4)(0.f), aI1 = (f32x4)(0.f);
    #pragma unroll
    for (int ks = 0; ks < 2; ++ks) {
        const int off = ks * 32 + 8 * q;
        sh8 xr0 = *reinterpret_cast<const sh8*>(&xbr[c16 * 72 + off]);
        sh8 xr1 = *reinterpret_cast<const sh8*>(&xbr[(16 + c16) * 72 + off]);
        sh8 xi0 = *reinterpret_cast<const sh8*>(&xbi[c16 * 72 + off]);
        sh8 xi1 = *reinterpret_cast<const sh8*>(&xbi[(16 + c16) * 72 + off]);
        sh8 br = *reinterpret_cast<const sh8*>(&rsr[(16 * w + c16) * 72 + off]);
        sh8 bi = *reinterpret_cast<const sh8*>(&rsi[(16 * w + c16) * 72 + off]);
        sh8 bn = *reinterpret_cast<const sh8*>(&rsn[(16 * w + c16) * 72 + off]);
        aR0 = __builtin_amdgcn_mfma_f32_16x16x32_bf16(xr0, br, aR0, 0, 0, 0);
        aR0 = __builtin_amdgcn_mfma_f32_16x16x32_bf16(xi0, bn, aR0, 0, 0, 0);
        aI0 = __builtin_amdgcn_mfma_f32_16x16x32_bf16(xr0, bi, aI0, 0, 0, 0);
        aI0 = __builtin_amdgcn_mfma_f32_16x16x32_bf16(xi0, br, aI0, 0, 0, 0);
        aR1 = __builtin_amdgcn_mfma_f32_16x16x32_bf16(xr1, br, aR1, 0, 0, 0);
        aR1 = __builtin_amdgcn_mfma_f32_16x16x32_bf16(xi1, bn, aR1, 0, 0, 0);
        aI1 = __builtin_amdgcn_mfma_f32_16x16x32_bf16(xr1, bi, aI1, 0, 0, 0);
        aI1 = __builtin_amdgcn_mfma_f32_16x16x32_bf16(xi1, br, aI1, 0, 0, 0);
    }
    float2* okrow = OK + (size_t)ij * 2048;
    #pragma unroll
    for (int reg = 0; reg < 4; ++reg) {
        okrow[(4 * q + reg) * 64 + 16 * w + c16]        = make_float2(aR0[reg], aI0[reg]);
        okrow[(16 + 4 * q + reg) * 64 + 16 * w + c16]   = make_float2(aR1[reg], aI1[reg]);
    }
}

// ---------------------------------------------------------------- inverse DFT (per b,o)  [frozen, round-24]
__launch_bounds__(256, 5)
__global__ void k_inv(const float2* __restrict__ OKg, const unsigned short* __restrict__ qxbg,
                      const unsigned short* __restrict__ qtbg, float* __restrict__ out) {
    __shared__ __align__(16) unsigned short t2br[4096];
    __shared__ __align__(16) unsigned short t2bi[4096];
    __shared__ __align__(16) unsigned short okr_t[1024];
    __shared__ __align__(16) unsigned short oki_t[1024];
    __shared__ float2 oks[441];
    const int t = threadIdx.x;
    const int bo = blockIdx.x;

    for (int k = t; k < 441; k += 256) oks[k] = OKg[(size_t)k * 2048 + bo];
    __syncthreads();
    for (int k = t; k < 1024; k += 256) {
        int j = k >> 5, i = k & 31;
        bool v = (j < 21) && (i < 21);
        float2 o = v ? oks[i * 21 + j] : make_float2(0.f, 0.f);
        okr_t[k] = v ? f2bf(o.x) : (unsigned short)0;
        oki_t[k] = v ? f2bf(o.y) : (unsigned short)0;
    }
    __syncthreads();
    const int lane = t & 63, w = t >> 6;
    const int c16 = lane & 15, q = lane >> 4;
    {
        const unsigned short* qxr = qxbg;
        const unsigned short* qxi = qxbg + 4096;
        const unsigned short* qxn = qxbg + 8192;
        sh8 ar0 = *reinterpret_cast<const sh8*>(okr_t + c16 * 32 + 8 * q);
        sh8 ar1 = *reinterpret_cast<const sh8*>(okr_t + (16 + c16) * 32 + 8 * q);
        sh8 ai0 = *reinterpret_cast<const sh8*>(oki_t + c16 * 32 + 8 * q);
        sh8 ai1 = *reinterpret_cast<const sh8*>(oki_t + (16 + c16) * 32 + 8 * q);
        #pragma unroll
        for (int nn = 0; nn < 2; ++nn) {
            int nt = 2 * w + nn;
            int nb = (16 * nt + c16) * 32 + 8 * q;
            sh8 br = *reinterpret_cast<const sh8*>(qxr + nb);
            sh8 bi = *reinterpret_cast<const sh8*>(qxi + nb);
            sh8 bn = *reinterpret_cast<const sh8*>(qxn + nb);
            f32x4 aR0 = (f32x4)(0.f), aI0 = (f32x4)(0.f);
            f32x4 aR1 = (f32x4)(0.f), aI1 = (f32x4)(0.f);
            aR0 = __builtin_amdgcn_mfma_f32_16x16x32_bf16(ar0, br, aR0, 0, 0, 0);
            aR0 = __builtin_amdgcn_mfma_f32_16x16x32_bf16(ai0, bn, aR0, 0, 0, 0);
            aI0 = __builtin_amdgcn_mfma_f32_16x16x32_bf16(ar0, bi, aI0, 0, 0, 0);
            aI0 = __builtin_amdgcn_mfma_f32_16x16x32_bf16(ai0, br, aI0, 0, 0, 0);
            aR1 = __builtin_amdgcn_mfma_f32_16x16x32_bf16(ar1, br, aR1, 0, 0, 0);
            aR1 = __builtin_amdgcn_mfma_f32_16x16x32_bf16(ai1, bn, aR1, 0, 0, 0);
            aI1 = __builtin_amdgcn_mfma_f32_16x16x32_bf16(ar1, bi, aI1, 0, 0, 0);
            aI1 = __builtin_amdgcn_mfma_f32_16x16x32_bf16(ai1, br, aI1, 0, 0, 0);
            int nrow = (16 * nt + c16) * 32;
            #pragma unroll
            for (int reg = 0; reg < 4; ++reg) {
                t2br[nrow + 4 * q + reg]      = f2bf(aR0[reg]);
                t2bi[nrow + 4 * q + reg]      = f2bf(-aI0[reg]);
                t2br[nrow + 16 + 4 * q + reg] = f2bf(aR1[reg]);
                t2bi[nrow + 16 + 4 * q + reg] = f2bf(-aI1[reg]);
            }
        }
    }
    __syncthreads();
    {
        const unsigned short* qtbr_l = qtbg;
        const unsigned short* qtbi_l = qtbg + 4096;
        sh8 ar0 = *reinterpret_cast<const sh8*>(t2br + (32 * w + c16) * 32 + 8 * q);
        sh8 ai0 = *reinterpret_cast<const sh8*>(t2bi + (32 * w + c16) * 32 + 8 * q);
        sh8 ar1 = *reinterpret_cast<const sh8*>(t2br + (32 * w + 16 + c16) * 32 + 8 * q);
        sh8 ai1 = *reinterpret_cast<const sh8*>(t2bi + (32 * w + 16 + c16) * 32 + 8 * q);
        float* og = out + (size_t)bo * 16384;
        #pragma unroll
        for (int mc = 0; mc < 8; ++mc) {
            sh8 br = *reinterpret_cast<const sh8*>(qtbr_l + (16 * mc + c16) * 32 + 8 * q);
            sh8 bi = *reinterpret_cast<const sh8*>(qtbi_l + (16 * mc + c16) * 32 + 8 * q);
            f32x4 acc0 = (f32x4)(0.f);
            acc0 = __builtin_amdgcn_mfma_f32_16x16x32_bf16(ar0, br, acc0, 0, 0, 0);
            acc0 = __builtin_amdgcn_mfma_f32_16x16x32_bf16(ai0, bi, acc0, 0, 0, 0);
            f32x4 acc1 = (f32x4)(0.f);
            acc1 = __builtin_amdgcn_mfma_f32_16x16x32_bf16(ar1, br, acc1, 0, 0, 0);
            acc1 = __builtin_amdgcn_mfma_f32_16x16x32_bf16(ai1, bi, acc1, 0, 0, 0);
            #pragma unroll
            for (int reg = 0; reg < 4; ++reg) {
                og[(32 * w + 4 * q + reg) * 128 + 16 * mc + c16]      = acc0[reg] * NORM;
                og[(32 * w + 16 + 4 * q + reg) * 128 + 16 * mc + c16] = acc1[reg] * NORM;
            }
        }
    }
}

// ---------------------------------------------------------------- launch
extern "C" void kernel_launch(void* const* d_in, const int* in_sizes, int n_in,
                              void* d_out, int out_size, void* d_ws, size_t ws_size,
                              hipStream_t stream) {
    const float* x   = (const float*)d_in[0];
    const float* wr  = (const float*)d_in[1];
    const float* wi  = (const float*)d_in[2];
    const float* thx = (const float*)d_in[3];
    const float* tht = (const float*)d_in[4];
    float* out = (float*)d_out;

    char* ws = (char*)d_ws;
    float2* W1 = (float2*)(ws);                                   // 1024 B
    unsigned short* wb  = (unsigned short*)(ws + 1024);           // 8192 B  -> ends 9216
    unsigned short* qxb = (unsigned short*)(ws + 9216);           // 24576 B -> ends 33792
    unsigned short* qtb = (unsigned short*)(ws + 33792);          // 16384 B -> ends 50176
    float2* Rt = (float2*)(ws + 64512);                           // 14450688 B
    float2* Xt = (float2*)(ws + 64512 + 14450688);                // [448][2048] f2 = 7340032 B
    float2* OK = (float2*)(ws + 64512 + 14450688 + 7340032);      // 7225344 B

    k_prep<<<449, 256, 0, stream>>>(thx, tht, wr, wi, W1, wb, qxb, qtb, Rt);
    k_fwd<<<2048, 256, 0, stream>>>(x, W1, wb, Xt);
    k_mix<<<441, 256, 0, stream>>>(Xt, Rt, OK);
    k_inv<<<2048, 256, 0, stream>>>(OK, qxb, qtb, out);
}